// Round 16
// baseline (234.279 us; speedup 1.0000x reference)
//
#include <hip/hip_runtime.h>
#include <hip/hip_bf16.h>

#define B_ 4
#define S_ 4096
#define D_ 256

typedef __attribute__((ext_vector_type(8))) short bf16x8;
typedef __attribute__((ext_vector_type(4))) short short4v;
typedef __attribute__((ext_vector_type(4))) float f32x4;

// round-to-nearest-even f32 -> bf16 bits (inputs finite)
static __device__ __forceinline__ unsigned short f2bf(float f) {
    unsigned int u = __float_as_uint(f);
    u += 0x7fffu + ((u >> 16) & 1u);
    return (unsigned short)(u >> 16);
}
static __device__ __forceinline__ float bf2f(unsigned short h) {
    return __uint_as_float(((unsigned int)h) << 16);
}
// packed f32x2 -> bf16x2 (RNE), single HW op (T12)
static __device__ __forceinline__ unsigned int cvtpk(float lo, float hi) {
    unsigned int r;
    asm("v_cvt_pk_bf16_f32 %0, %1, %2" : "=v"(r) : "v"(lo), "v"(hi));
    return r;
}

// async global -> LDS DMA, 16B/lane: LDS gets base + lane*16 (linear);
// global source is per-lane (pre-swizzled to realize swizzled LDS layouts).
static __device__ __forceinline__ void gload16(const void* g, void* l) {
    __builtin_amdgcn_global_load_lds(
        (const __attribute__((address_space(1))) unsigned int*)g,
        (__attribute__((address_space(3))) unsigned int*)l, 16, 0, 0);
}

// 16x16x16 bf16 MFMA (A/B = 4 bf16 = 2 VGPRs, C/D = 4 f32)
#if __has_builtin(__builtin_amdgcn_mfma_f32_16x16x16bf16_1k)
#define MFMA16(a, b, c) __builtin_amdgcn_mfma_f32_16x16x16bf16_1k(a, b, c, 0, 0, 0)
#elif __has_builtin(__builtin_amdgcn_mfma_f32_16x16x16_bf16)
#define MFMA16(a, b, c) __builtin_amdgcn_mfma_f32_16x16x16_bf16(a, b, c, 0, 0, 0)
#else
static __device__ __forceinline__ f32x4 mfma16_asm(short4v a, short4v b, f32x4 c) {
    asm volatile("v_mfma_f32_16x16x16_bf16 %0, %1, %2, %0"
                 : "+v"(c) : "v"(a), "v"(b));
    return c;
}
#define MFMA16(a, b, c) mfma16_asm(a, b, c)
#endif

// ---------------------------------------------------------------------------
// Kernel 1 (certified r6-r14): QKV = X @ W^T + b, f32 in, bf16 out.
// Q,K row-major [b*S+s][256]; V transposed Vt[b][d][s]. BM=BN=BK=64.
// ---------------------------------------------------------------------------
__global__ __launch_bounds__(256) void qkv_proj(
    const float* __restrict__ X, const float* __restrict__ W,
    const float* __restrict__ bias,
    unsigned short* __restrict__ Qb, unsigned short* __restrict__ Kb,
    unsigned short* __restrict__ Vt)
{
    __shared__ __align__(16) unsigned short As[64 * 64];
    __shared__ __align__(16) unsigned short Bs[64 * 64];

    const int tid  = threadIdx.x;
    const int lane = tid & 63;
    const int wid  = tid >> 6;
    const int wm   = wid >> 1, wn = wid & 1;
    const int c    = lane & 15, q4 = lane >> 4;
    const int gm0  = blockIdx.x * 64;
    const int gn0  = blockIdx.y * 64;
    const int sr   = tid >> 2;
    const int sc   = (tid & 3) * 16;

    f32x4 acc[2][2] = {};

    for (int kt = 0; kt < 4; ++kt) {
        const int k0 = kt * 64;
        {
            const float4* ga = (const float4*)(X + (size_t)(gm0 + sr) * D_ + k0 + sc);
            const float4* gb = (const float4*)(W + (size_t)(gn0 + sr) * D_ + k0 + sc);
            float4 a0 = ga[0], a1 = ga[1], a2 = ga[2], a3 = ga[3];
            float4 b0 = gb[0], b1 = gb[1], b2 = gb[2], b3 = gb[3];
            float af[16] = {a0.x,a0.y,a0.z,a0.w, a1.x,a1.y,a1.z,a1.w,
                            a2.x,a2.y,a2.z,a2.w, a3.x,a3.y,a3.z,a3.w};
            float bf[16] = {b0.x,b0.y,b0.z,b0.w, b1.x,b1.y,b1.z,b1.w,
                            b2.x,b2.y,b2.z,b2.w, b3.x,b3.y,b3.z,b3.w};
            bf16x8 av0, av1, bv0, bv1;
            #pragma unroll
            for (int j = 0; j < 8; ++j) {
                av0[j] = (short)f2bf(af[j]);     av1[j] = (short)f2bf(af[8 + j]);
                bv0[j] = (short)f2bf(bf[j]);     bv1[j] = (short)f2bf(bf[8 + j]);
            }
            const int sw = (sr & 7) << 3;
            *(bf16x8*)&As[sr * 64 + ((sc + 0) ^ sw)] = av0;
            *(bf16x8*)&As[sr * 64 + ((sc + 8) ^ sw)] = av1;
            *(bf16x8*)&Bs[sr * 64 + ((sc + 0) ^ sw)] = bv0;
            *(bf16x8*)&Bs[sr * 64 + ((sc + 8) ^ sw)] = bv1;
        }
        __syncthreads();
        const int sw = (c & 7) << 3;
        #pragma unroll
        for (int kk = 0; kk < 64; kk += 32) {
            bf16x8 afr[2], bfr[2];
            #pragma unroll
            for (int mf = 0; mf < 2; ++mf) {
                const int row = wm * 32 + mf * 16 + c;
                afr[mf] = *(const bf16x8*)&As[row * 64 + ((kk + 8 * q4) ^ sw)];
            }
            #pragma unroll
            for (int nf = 0; nf < 2; ++nf) {
                const int row = wn * 32 + nf * 16 + c;
                bfr[nf] = *(const bf16x8*)&Bs[row * 64 + ((kk + 8 * q4) ^ sw)];
            }
            #pragma unroll
            for (int mf = 0; mf < 2; ++mf)
                #pragma unroll
                for (int nf = 0; nf < 2; ++nf)
                    acc[mf][nf] = __builtin_amdgcn_mfma_f32_16x16x32_bf16(
                        afr[mf], bfr[nf], acc[mf][nf], 0, 0, 0);
        }
        __syncthreads();
    }

    const int b  = gm0 >> 12;
    const int s0 = gm0 & 4095;
    #pragma unroll
    for (int mf = 0; mf < 2; ++mf) {
        #pragma unroll
        for (int nf = 0; nf < 2; ++nf) {
            const int e  = gn0 + wn * 32 + nf * 16 + c;
            const float bv = bias[e];
            const int srow0 = s0 + wm * 32 + mf * 16 + 4 * q4;
            if (e < 256) {
                #pragma unroll
                for (int i = 0; i < 4; ++i)
                    Qb[((size_t)b * S_ + srow0 + i) * D_ + e] =
                        f2bf(acc[mf][nf][i] + bv);
            } else if (e < 512) {
                #pragma unroll
                for (int i = 0; i < 4; ++i)
                    Kb[((size_t)b * S_ + srow0 + i) * D_ + (e - 256)] =
                        f2bf(acc[mf][nf][i] + bv);
            } else {
                short4v pv;
                #pragma unroll
                for (int i = 0; i < 4; ++i)
                    pv[i] = (short)f2bf(acc[mf][nf][i] + bv);
                *(short4v*)&Vt[((size_t)(b * D_ + (e - 512))) * S_ + srow0] = pv;
            }
        }
    }
}

// ---------------------------------------------------------------------------
// Kernel 2: flash attention. 512 thr = 8 waves = 2 row-groups(32 q) x
// 4 key-quarters(1024 keys); 16-key steps x 64. Each wave reads each K/V
// fragment ONCE for TWO Q/P fragments (halves LDS reads per q.key), and the
// 16x16x16 PV consumes P fully in-lane (zero P-assembly shuffles):
//   QK (swapped, 16x16x32): sacc_{a,b}[r] = S[key 4g+r][q0(+16)+qi]
//   PV (swapped, 16x16x16): B-frag k=4g+j == lane's own sacc rows.
// LDS buffers 2x64KB: {K q0..q3 [16][512B] slot^=row | V q0..q3 [256][32B]
// 16B-half^=(d>>2)&1}; DMA staging 64KB/step. 4-quarter merge via LDS tree.
// ---------------------------------------------------------------------------
__global__ __launch_bounds__(512, 2) void attn_fwd(
    const unsigned short* __restrict__ Qb, const unsigned short* __restrict__ Kb,
    const unsigned short* __restrict__ Vt, float* __restrict__ Out)
{
    __shared__ __align__(16) char smem[135680];
    // [0,131072): 2 x 64KB staging buffers
    // epilogue: R1 f32[64][261] at 0; R3 at 66816 (alias staging, dead then)
    // Mbuf f32[64][4] at 133632; Lbuf f32[64][4] at 134656

    const int bid  = blockIdx.x;
    const int xcd  = bid & 7;
    const int tile = (xcd >> 1) * 64 + (bid >> 3) * 2 + (xcd & 1); // [0,256)
    const int gr0  = tile * 64;
    const int b    = gr0 >> 12;

    const int tid  = threadIdx.x;
    const int wid  = tid >> 6, lane = tid & 63;
    const int qi   = lane & 15, g = lane >> 4;
    const int rg   = wid & 1;             // row group (32 q)
    const int kq   = wid >> 1;            // key quarter (compute role)
    const int q0   = gr0 + rg * 32;
    const float C  = 0.09016844005556021f;   // log2(e)/sqrt(256)
    const float THR = 40.0f;

    // Q B-fragments for q = q0+qi (a) and q0+16+qi (b): d = m*32 + 8g + j
    bf16x8 qfa[8], qfb[8];
    {
        const size_t qra = (size_t)(q0 + qi) * D_ + 8 * g;
        const size_t qrb = (size_t)(q0 + 16 + qi) * D_ + 8 * g;
        #pragma unroll
        for (int m = 0; m < 8; ++m) {
            qfa[m] = *(const bf16x8*)&Qb[qra + m * 32];
            qfb[m] = *(const bf16x8*)&Qb[qrb + m * 32];
        }
    }

    const unsigned short* Kbb = Kb + (size_t)b * S_ * D_;
    const unsigned short* Vtb = Vt + (size_t)b * D_ * S_;

    // --- DMA staging roles (8 gload16/thread): waves 0-3 K q, 4-7 V q ---
    const int isK = (wid < 4);
    const int sq  = isK ? wid : wid - 4;  // staged quarter
    int soff[8], doff[8];
    if (isK) {
        #pragma unroll
        for (int j = 0; j < 8; ++j) {
            const int r0 = 2 * j + (lane >> 5);          // tile row 0..15
            soff[j] = (sq * 1024 + r0) * 256 + (((lane & 31) ^ r0) << 3);
            doff[j] = sq * 8192 + j * 1024;
        }
    } else {
        #pragma unroll
        for (int j = 0; j < 8; ++j) {
            const int d = 32 * j + (lane >> 1);          // d row 0..255
            soff[j] = d * S_ + sq * 1024 +
                      (((lane & 1) ^ ((lane >> 3) & 1)) << 3);
            doff[j] = 32768 + sq * 8192 + j * 1024;
        }
    }
    const unsigned short* sbase = isK ? Kbb : Vtb;

    f32x4 oA[16] = {}, oB[16] = {};
    float m0a = -1.0e30f, l0a = 0.0f, m0b = -1.0e30f, l0b = 0.0f;

    // --- prologue: DMA tile 0 into buffer 0 ---
    #pragma unroll
    for (int j = 0; j < 8; ++j)
        gload16(sbase + soff[j], smem + doff[j]);
    __builtin_amdgcn_s_waitcnt(0);
    __syncthreads();

    const int NS = 64;
    int p = 0;
    const int vbyte = (((g >> 1) ^ ((qi >> 2) & 1)) << 4) + ((g & 1) << 3);

    for (int s = 0; s < NS; ++s) {
        // ---- issue DMA for tile s+1 into buffer p^1 ----
        if (s + 1 < NS) {
            const unsigned short* sb = sbase + (isK ? (s + 1) * 4096
                                                    : (s + 1) * 16);
            const int bufo = (p ^ 1) * 65536;
            #pragma unroll
            for (int j = 0; j < 8; ++j)
                gload16(sb + soff[j], smem + bufo + doff[j]);
        }

        const char* Ksb = smem + p * 65536 + kq * 8192;
        const char* Vsb = smem + p * 65536 + 32768 + kq * 8192;

        // ---- QK^T (swapped): one K read feeds both Q chains ----
        f32x4 sa = {}, sb2 = {};
        __builtin_amdgcn_s_setprio(1);
        #pragma unroll
        for (int m = 0; m < 8; ++m) {
            bf16x8 kf = *(const bf16x8*)(Ksb + qi * 512 +
                                         ((((m << 2) + g) ^ qi) << 4));
            sa  = __builtin_amdgcn_mfma_f32_16x16x32_bf16(kf, qfa[m], sa, 0, 0, 0);
            sb2 = __builtin_amdgcn_mfma_f32_16x16x32_bf16(kf, qfb[m], sb2, 0, 0, 0);
        }
        __builtin_amdgcn_s_setprio(0);

        // ---- per-lane softmax, two chains ----
        float ra = fmaxf(fmaxf(sa[0], sa[1]), fmaxf(sa[2], sa[3]));
        float rb = fmaxf(fmaxf(sb2[0], sb2[1]), fmaxf(sb2[2], sb2[3]));
        ra = fmaxf(ra, __shfl_xor(ra, 16));  ra = fmaxf(ra, __shfl_xor(ra, 32));
        rb = fmaxf(rb, __shfl_xor(rb, 16));  rb = fmaxf(rb, __shfl_xor(rb, 32));

        if (__any((ra > m0a + THR) || (rb > m0b + THR))) {
            const float mna = fmaxf(m0a, ra), mnb = fmaxf(m0b, rb);
            const float ca = exp2f((m0a - mna) * C);
            const float cb = exp2f((m0b - mnb) * C);
            m0a = mna; l0a *= ca;  m0b = mnb; l0b *= cb;
            #pragma unroll
            for (int dc = 0; dc < 16; ++dc)
                #pragma unroll
                for (int r = 0; r < 4; ++r) {
                    oA[dc][r] *= ca;  oB[dc][r] *= cb;
                }
        }

        float pa[4], pb[4];
        float rsa = 0.f, rsb = 0.f;
        #pragma unroll
        for (int r = 0; r < 4; ++r) {
            pa[r] = exp2f((sa[r]  - m0a) * C);  rsa += pa[r];
            pb[r] = exp2f((sb2[r] - m0b) * C);  rsb += pb[r];
        }
        rsa += __shfl_xor(rsa, 16);  rsa += __shfl_xor(rsa, 32);  l0a += rsa;
        rsb += __shfl_xor(rsb, 16);  rsb += __shfl_xor(rsb, 32);  l0b += rsb;

        // ---- P stays in-lane: pack to B-fragments (k = 4g + j) ----
        union U { unsigned int w[2]; short4v v; } ua, ub;
        ua.w[0] = cvtpk(pa[0], pa[1]);  ua.w[1] = cvtpk(pa[2], pa[3]);
        ub.w[0] = cvtpk(pb[0], pb[1]);  ub.w[1] = cvtpk(pb[2], pb[3]);

        // ---- O^T += V-frag x P : one V read feeds both chains ----
        __builtin_amdgcn_s_setprio(1);
        #pragma unroll
        for (int dc = 0; dc < 16; ++dc) {
            short4v vf = *(const short4v*)(Vsb + (dc * 16 + qi) * 32 + vbyte);
            oA[dc] = MFMA16(vf, ua.v, oA[dc]);
            oB[dc] = MFMA16(vf, ub.v, oB[dc]);
        }
        __builtin_amdgcn_s_setprio(0);

        __syncthreads();   // implicit vmcnt(0): tile s+1 DMAs complete
        p ^= 1;
    }

    // ---- merge across 4 key quarters ----
    float* Mbuf = (float*)(smem + 133632);
    float* Lbuf = (float*)(smem + 134656);
    const int rowA = rg * 32 + qi, rowB = rowA + 16;

    if (g == 0) { Mbuf[rowA * 4 + kq] = m0a;  Mbuf[rowB * 4 + kq] = m0b; }
    __syncthreads();

    {
        const float* ma = &Mbuf[rowA * 4];
        const float* mb = &Mbuf[rowB * 4];
        const float gma = fmaxf(fmaxf(ma[0], ma[1]), fmaxf(ma[2], ma[3]));
        const float gmb = fmaxf(fmaxf(mb[0], mb[1]), fmaxf(mb[2], mb[3]));
        const float ca = exp2f((m0a - gma) * C);
        const float cb = exp2f((m0b - gmb) * C);
        l0a *= ca;  l0b *= cb;
        #pragma unroll
        for (int dc = 0; dc < 16; ++dc)
            #pragma unroll
            for (int r = 0; r < 4; ++r) {
                oA[dc][r] *= ca;  oB[dc][r] *= cb;
            }
    }
    if (g == 0) { Lbuf[rowA * 4 + kq] = l0a;  Lbuf[rowB * 4 + kq] = l0b; }
    __syncthreads();

    const float* la = &Lbuf[rowA * 4];
    const float* lb = &Lbuf[rowB * 4];
    const float invA = 1.0f / (la[0] + la[1] + la[2] + la[3]);
    const float invB = 1.0f / (lb[0] + lb[1] + lb[2] + lb[3]);

    float* R1 = (float*)smem;                 // [64][261]
    float* R3 = (float*)(smem + 66816);       // [64][261]

    if (kq == 1 || kq == 3) {
        float* R = (kq == 1) ? R1 : R3;
        #pragma unroll
        for (int dc = 0; dc < 16; ++dc)
            #pragma unroll
            for (int r = 0; r < 4; ++r) {
                const int col = dc * 16 + 4 * g + r;
                R[rowA * 261 + col] = oA[dc][r];
                R[rowB * 261 + col] = oB[dc][r];
            }
    }
    __syncthreads();

    if (kq == 0) {
        #pragma unroll
        for (int dc = 0; dc < 16; ++dc)
            #pragma unroll
            for (int r = 0; r < 4; ++r) {
                const int col = dc * 16 + 4 * g + r;
                oA[dc][r] += R1[rowA * 261 + col];
                oB[dc][r] += R1[rowB * 261 + col];
            }
    }
    if (kq == 2) {
        #pragma unroll
        for (int dc = 0; dc < 16; ++dc)
            #pragma unroll
            for (int r = 0; r < 4; ++r) {
                const int col = dc * 16 + 4 * g + r;
                oA[dc][r] += R3[rowA * 261 + col];
                oB[dc][r] += R3[rowB * 261 + col];
            }
    }
    __syncthreads();
    if (kq == 2) {
        #pragma unroll
        for (int dc = 0; dc < 16; ++dc)
            #pragma unroll
            for (int r = 0; r < 4; ++r) {
                const int col = dc * 16 + 4 * g + r;
                R3[rowA * 261 + col] = oA[dc][r];
                R3[rowB * 261 + col] = oB[dc][r];
            }
    }
    __syncthreads();

    if (kq == 0) {
        #pragma unroll
        for (int dc = 0; dc < 16; ++dc)
            #pragma unroll
            for (int r = 0; r < 4; ++r) {
                const int col = dc * 16 + 4 * g + r;
                Out[(size_t)(q0 + qi) * D_ + col] =
                    (oA[dc][r] + R3[rowA * 261 + col]) * invA;
                Out[(size_t)(q0 + 16 + qi) * D_ + col] =
                    (oB[dc][r] + R3[rowB * 261 + col]) * invB;
            }
    }
}

extern "C" void kernel_launch(void* const* d_in, const int* in_sizes, int n_in,
                              void* d_out, int out_size, void* d_ws, size_t ws_size,
                              hipStream_t stream) {
    (void)out_size; (void)ws_size;
    const void *Xp = nullptr, *Wp = nullptr, *bp = nullptr;
    for (int i = 0; i < n_in; ++i) {
        if      (in_sizes[i] == B_ * S_ * D_) Xp = d_in[i];
        else if (in_sizes[i] == 3 * D_ * D_)  Wp = d_in[i];
        else if (in_sizes[i] == 3 * D_)       bp = d_in[i];
    }
    if (!Xp) Xp = d_in[0];
    if (!Wp) Wp = d_in[1];
    if (!bp) bp = d_in[2];

    float* Out = (float*)d_out;                                 // [B*S][256] f32

    unsigned short* Qb = (unsigned short*)d_ws;                 // 8 MiB
    unsigned short* Kb = Qb + (size_t)B_ * S_ * D_;             // 8 MiB
    unsigned short* Vt = Kb + (size_t)B_ * S_ * D_;             // 8 MiB
    // ws needed: 24 MiB

    dim3 pgrid(256, 12);
    qkv_proj<<<pgrid, 256, 0, stream>>>((const float*)Xp, (const float*)Wp,
                                        (const float*)bp, Qb, Kb, Vt);
    attn_fwd<<<256, 512, 0, stream>>>(Qb, Kb, Vt, Out);
}

// Round 17
// 157.943 us; speedup vs baseline: 1.4833x; 1.4833x over previous
//
#include <hip/hip_runtime.h>
#include <hip/hip_bf16.h>

#define B_ 4
#define S_ 4096
#define D_ 256

typedef __attribute__((ext_vector_type(8))) short bf16x8;
typedef __attribute__((ext_vector_type(4))) short short4v;
typedef __attribute__((ext_vector_type(4))) float f32x4;

// round-to-nearest-even f32 -> bf16 bits (inputs finite)
static __device__ __forceinline__ unsigned short f2bf(float f) {
    unsigned int u = __float_as_uint(f);
    u += 0x7fffu + ((u >> 16) & 1u);
    return (unsigned short)(u >> 16);
}
static __device__ __forceinline__ float bf2f(unsigned short h) {
    return __uint_as_float(((unsigned int)h) << 16);
}
// packed f32x2 -> bf16x2 (RNE), single HW op (T12)
static __device__ __forceinline__ unsigned int cvtpk(float lo, float hi) {
    unsigned int r;
    asm("v_cvt_pk_bf16_f32 %0, %1, %2" : "=v"(r) : "v"(lo), "v"(hi));
    return r;
}

// async global -> LDS DMA, 16B/lane: LDS gets base + lane*16 (linear);
// global source is per-lane (pre-swizzled to realize swizzled LDS layouts).
static __device__ __forceinline__ void gload16(const void* g, void* l) {
    __builtin_amdgcn_global_load_lds(
        (const __attribute__((address_space(1))) unsigned int*)g,
        (__attribute__((address_space(3))) unsigned int*)l, 16, 0, 0);
}

// ---------------------------------------------------------------------------
// Kernel 1 (certified r6-r16): QKV = X @ W^T + b, f32 in, bf16 out.
// Q,K row-major [b*S+s][256]; V transposed Vt[b][d][s]. BM=BN=BK=64.
// ---------------------------------------------------------------------------
__global__ __launch_bounds__(256) void qkv_proj(
    const float* __restrict__ X, const float* __restrict__ W,
    const float* __restrict__ bias,
    unsigned short* __restrict__ Qb, unsigned short* __restrict__ Kb,
    unsigned short* __restrict__ Vt)
{
    __shared__ __align__(16) unsigned short As[64 * 64];
    __shared__ __align__(16) unsigned short Bs[64 * 64];

    const int tid  = threadIdx.x;
    const int lane = tid & 63;
    const int wid  = tid >> 6;
    const int wm   = wid >> 1, wn = wid & 1;
    const int c    = lane & 15, q4 = lane >> 4;
    const int gm0  = blockIdx.x * 64;
    const int gn0  = blockIdx.y * 64;
    const int sr   = tid >> 2;
    const int sc   = (tid & 3) * 16;

    f32x4 acc[2][2] = {};

    for (int kt = 0; kt < 4; ++kt) {
        const int k0 = kt * 64;
        {
            const float4* ga = (const float4*)(X + (size_t)(gm0 + sr) * D_ + k0 + sc);
            const float4* gb = (const float4*)(W + (size_t)(gn0 + sr) * D_ + k0 + sc);
            float4 a0 = ga[0], a1 = ga[1], a2 = ga[2], a3 = ga[3];
            float4 b0 = gb[0], b1 = gb[1], b2 = gb[2], b3 = gb[3];
            float af[16] = {a0.x,a0.y,a0.z,a0.w, a1.x,a1.y,a1.z,a1.w,
                            a2.x,a2.y,a2.z,a2.w, a3.x,a3.y,a3.z,a3.w};
            float bf[16] = {b0.x,b0.y,b0.z,b0.w, b1.x,b1.y,b1.z,b1.w,
                            b2.x,b2.y,b2.z,b2.w, b3.x,b3.y,b3.z,b3.w};
            bf16x8 av0, av1, bv0, bv1;
            #pragma unroll
            for (int j = 0; j < 8; ++j) {
                av0[j] = (short)f2bf(af[j]);     av1[j] = (short)f2bf(af[8 + j]);
                bv0[j] = (short)f2bf(bf[j]);     bv1[j] = (short)f2bf(bf[8 + j]);
            }
            const int sw = (sr & 7) << 3;
            *(bf16x8*)&As[sr * 64 + ((sc + 0) ^ sw)] = av0;
            *(bf16x8*)&As[sr * 64 + ((sc + 8) ^ sw)] = av1;
            *(bf16x8*)&Bs[sr * 64 + ((sc + 0) ^ sw)] = bv0;
            *(bf16x8*)&Bs[sr * 64 + ((sc + 8) ^ sw)] = bv1;
        }
        __syncthreads();
        const int sw = (c & 7) << 3;
        #pragma unroll
        for (int kk = 0; kk < 64; kk += 32) {
            bf16x8 afr[2], bfr[2];
            #pragma unroll
            for (int mf = 0; mf < 2; ++mf) {
                const int row = wm * 32 + mf * 16 + c;
                afr[mf] = *(const bf16x8*)&As[row * 64 + ((kk + 8 * q4) ^ sw)];
            }
            #pragma unroll
            for (int nf = 0; nf < 2; ++nf) {
                const int row = wn * 32 + nf * 16 + c;
                bfr[nf] = *(const bf16x8*)&Bs[row * 64 + ((kk + 8 * q4) ^ sw)];
            }
            #pragma unroll
            for (int mf = 0; mf < 2; ++mf)
                #pragma unroll
                for (int nf = 0; nf < 2; ++nf)
                    acc[mf][nf] = __builtin_amdgcn_mfma_f32_16x16x32_bf16(
                        afr[mf], bfr[nf], acc[mf][nf], 0, 0, 0);
        }
        __syncthreads();
    }

    const int b  = gm0 >> 12;
    const int s0 = gm0 & 4095;
    #pragma unroll
    for (int mf = 0; mf < 2; ++mf) {
        #pragma unroll
        for (int nf = 0; nf < 2; ++nf) {
            const int e  = gn0 + wn * 32 + nf * 16 + c;
            const float bv = bias[e];
            const int srow0 = s0 + wm * 32 + mf * 16 + 4 * q4;
            if (e < 256) {
                #pragma unroll
                for (int i = 0; i < 4; ++i)
                    Qb[((size_t)b * S_ + srow0 + i) * D_ + e] =
                        f2bf(acc[mf][nf][i] + bv);
            } else if (e < 512) {
                #pragma unroll
                for (int i = 0; i < 4; ++i)
                    Kb[((size_t)b * S_ + srow0 + i) * D_ + (e - 256)] =
                        f2bf(acc[mf][nf][i] + bv);
            } else {
                short4v pv;
                #pragma unroll
                for (int i = 0; i < 4; ++i)
                    pv[i] = (short)f2bf(acc[mf][nf][i] + bv);
                *(short4v*)&Vt[((size_t)(b * D_ + (e - 512))) * S_ + srow0] = pv;
            }
        }
    }
}

// ---------------------------------------------------------------------------
// Kernel 2 (r15 best, certified 137.8 us): flash attention. 512 threads =
// 8 waves = 4 row-groups(16 q) x 2 key-halves -> 2 waves/SIMD.
// QK swapped: sacc[kc] = mfma(Kfrag, Qfrag); PV swapped:
// o[dc] = mfma(Vt-frag, P^T-frag) -> per-lane scalar softmax state.
// DMA staging (global_load_lds), double-buffered 2x64KB. T5 setprio on
// MFMA clusters.
// ---------------------------------------------------------------------------
__global__ __launch_bounds__(512, 2) void attn_fwd(
    const unsigned short* __restrict__ Qb, const unsigned short* __restrict__ Kb,
    const unsigned short* __restrict__ Vt, float* __restrict__ Out)
{
    __shared__ __align__(16) char smem[132096];

    const int bid  = blockIdx.x;
    const int xcd  = bid & 7;
    const int tile = (xcd >> 1) * 64 + (bid >> 3) * 2 + (xcd & 1); // [0,256)
    const int gr0  = tile * 64;
    const int b    = gr0 >> 12;

    const int tid  = threadIdx.x;
    const int wid  = tid >> 6, lane = tid & 63;
    const int qi   = lane & 15, g = lane >> 4;
    const int rg   = wid & 3;             // row group (16 rows)
    const int kh   = wid >> 2;            // key half (compute role)
    const int q0   = gr0 + rg * 16;
    const float C  = 0.09016844005556021f;   // log2(e)/sqrt(256)
    const float THR = 40.0f;

    // Q fragments (B operand): lane col = qi; d = m*32 + 8g + j
    bf16x8 qf[8];
    {
        const size_t qrow = (size_t)(q0 + qi) * D_ + 8 * g;
        #pragma unroll
        for (int m = 0; m < 8; ++m)
            qf[m] = *(const bf16x8*)&Qb[qrow + m * 32];
    }

    const unsigned short* Kbb = Kb + (size_t)b * S_ * D_;
    const unsigned short* Vtb = Vt + (size_t)b * D_ * S_;

    // --- DMA staging roles (8 gload16/thread): waves 0-3 K, 4-7 V ---
    const int isK = (wid < 4);
    const int sth = (wid >> 1) & 1;       // staged key half
    const int sub = wid & 1;              // sub-range within half
    int soff[8];                          // per-lane element offsets (step-inv)
    int doff[8];                          // LDS byte offsets within buffer
    if (isK) {
        const int l5 = lane >> 5, i5 = lane & 31;
        #pragma unroll
        for (int j = 0; j < 8; ++j) {
            const int r0 = sub * 16 + 2 * j + l5;       // tile row 0..31
            soff[j] = (sth * 2048 + r0) * 256 + ((i5 ^ r0) << 3);
            doff[j] = sth * 16384 + (sub * 16 + 2 * j) * 512;
        }
    } else {
        #pragma unroll
        for (int j = 0; j < 8; ++j) {
            const int d = sub * 128 + 16 * j + (lane >> 2);
            soff[j] = d * S_ + sth * 2048 + ((((lane & 3) ^ ((lane >> 3) & 3))) << 3);
            doff[j] = 32768 + sth * 16384 + (sub * 128 + 16 * j) * 64;
        }
    }
    const unsigned short* sbase = isK ? Kbb : Vtb;

    float* Mbuf = (float*)(smem + 131072);
    float* Lbuf = (float*)(smem + 131584);

    f32x4 o[16] = {};
    float m0 = -1.0e30f, l0 = 0.0f;

    // --- prologue: DMA tile 0 into buffer 0 ---
    #pragma unroll
    for (int j = 0; j < 8; ++j)
        gload16(sbase + soff[j], smem + doff[j]);
    __builtin_amdgcn_s_waitcnt(0);
    __syncthreads();

    const int NS = 64;
    int p = 0;
    const int vsw = (g ^ ((qi >> 1) & 3)) << 4;   // V read swizzle (lane-const)

    for (int s = 0; s < NS; ++s) {
        // ---- issue DMA for tile s+1 into buffer p^1 (step top: max slack) ----
        if (s + 1 < NS) {
            const unsigned short* sb = sbase + (isK ? (s + 1) * 32 * 256
                                                    : (s + 1) * 32);
            const int bufo = (p ^ 1) * 65536;
            #pragma unroll
            for (int j = 0; j < 8; ++j)
                gload16(sb + soff[j], smem + bufo + doff[j]);
        }

        const char* Ksb = smem + p * 65536 + kh * 16384;
        const char* Vsb = smem + p * 65536 + 32768 + kh * 16384;

        // ---- QK^T (swapped), 2 independent chains (T5: setprio) ----
        f32x4 sacc[2] = {};
        __builtin_amdgcn_s_setprio(1);
        #pragma unroll
        for (int kc = 0; kc < 2; ++kc) {
            const int kr = kc * 16 + qi;
            const char* krow = Ksb + kr * 512;
            #pragma unroll
            for (int m = 0; m < 8; ++m) {
                bf16x8 kf = *(const bf16x8*)(krow + (((4 * m + g) ^ kr) << 4));
                sacc[kc] = __builtin_amdgcn_mfma_f32_16x16x32_bf16(
                    kf, qf[m], sacc[kc], 0, 0, 0);
            }
        }
        __builtin_amdgcn_s_setprio(0);

        // ---- per-lane softmax (q = qi): 8 local + 2 cross-group shfl ----
        float rmax = fmaxf(fmaxf(fmaxf(sacc[0][0], sacc[0][1]),
                                 fmaxf(sacc[0][2], sacc[0][3])),
                           fmaxf(fmaxf(sacc[1][0], sacc[1][1]),
                                 fmaxf(sacc[1][2], sacc[1][3])));
        rmax = fmaxf(rmax, __shfl_xor(rmax, 16));
        rmax = fmaxf(rmax, __shfl_xor(rmax, 32));

        if (__any(rmax > m0 + THR)) {
            const float mn = fmaxf(m0, rmax);
            const float corr = exp2f((m0 - mn) * C);
            m0 = mn;
            l0 *= corr;
            #pragma unroll
            for (int dc = 0; dc < 16; ++dc)
                #pragma unroll
                for (int r = 0; r < 4; ++r) o[dc][r] *= corr;
        }

        float p8[2][4];
        float rsum = 0.f;
        #pragma unroll
        for (int kc = 0; kc < 2; ++kc)
            #pragma unroll
            for (int r = 0; r < 4; ++r) {
                p8[kc][r] = exp2f((sacc[kc][r] - m0) * C);
                rsum += p8[kc][r];
            }
        rsum += __shfl_xor(rsum, 16);
        rsum += __shfl_xor(rsum, 32);
        l0 += rsum;

        // ---- pack P to bf16 pairs (HW cvt_pk) ----
        unsigned int pk0[2], pk1[2];
        pk0[0] = cvtpk(p8[0][0], p8[0][1]);  pk0[1] = cvtpk(p8[0][2], p8[0][3]);
        pk1[0] = cvtpk(p8[1][0], p8[1][1]);  pk1[1] = cvtpk(p8[1][2], p8[1][3]);

        // ---- assemble P^T B-fragment: k = 8g + j for own q ----
        const int A0 = qi + ((g & 1) << 5);   // src lane: group (g&1)*2
        const int A1 = A0 + 16;
        const unsigned int s00 = __shfl(pk0[0], A0), s01 = __shfl(pk0[1], A0);
        const unsigned int s02 = __shfl(pk0[0], A1), s03 = __shfl(pk0[1], A1);
        const unsigned int s10 = __shfl(pk1[0], A0), s11 = __shfl(pk1[1], A0);
        const unsigned int s12 = __shfl(pk1[0], A1), s13 = __shfl(pk1[1], A1);
        const bool hk = (g >> 1);             // which kc this lane needs
        union U { unsigned int w[4]; bf16x8 v; } pa;
        pa.w[0] = hk ? s10 : s00;  pa.w[1] = hk ? s11 : s01;
        pa.w[2] = hk ? s12 : s02;  pa.w[3] = hk ? s13 : s03;

        // ---- O^T += Vt-frag x P^T : 16 d-chunks (T5: setprio) ----
        __builtin_amdgcn_s_setprio(1);
        #pragma unroll
        for (int dc = 0; dc < 16; ++dc) {
            bf16x8 vf = *(const bf16x8*)(Vsb + (dc * 16 + qi) * 64 + vsw);
            o[dc] = __builtin_amdgcn_mfma_f32_16x16x32_bf16(vf, pa.v, o[dc], 0, 0, 0);
        }
        __builtin_amdgcn_s_setprio(0);

        __syncthreads();   // implicit vmcnt(0): tile s+1 DMAs complete
        p ^= 1;
    }

    // ---- merge across key halves (per-lane scalar state) ----
    const int qidx = rg * 16 + qi;            // block-local row
    if (g == 0) Mbuf[qidx * 2 + kh] = m0;
    __syncthreads();

    {
        const float gm = fmaxf(Mbuf[qidx * 2], Mbuf[qidx * 2 + 1]);
        const float corr = exp2f((m0 - gm) * C);
        l0 *= corr;
        #pragma unroll
        for (int dc = 0; dc < 16; ++dc)
            #pragma unroll
            for (int r = 0; r < 4; ++r) o[dc][r] *= corr;
    }
    if (g == 0) Lbuf[qidx * 2 + kh] = l0;

    float* Obuf = (float*)smem;               // [64][260], aliases KV buffers
    if (kh == 1) {
        #pragma unroll
        for (int dc = 0; dc < 16; ++dc)
            #pragma unroll
            for (int r = 0; r < 4; ++r)
                Obuf[qidx * 260 + dc * 16 + 4 * g + r] = o[dc][r];
    }
    __syncthreads();

    if (kh == 0) {
        const float inv = 1.0f / (Lbuf[qidx * 2] + Lbuf[qidx * 2 + 1]);
        #pragma unroll
        for (int dc = 0; dc < 16; ++dc)
            #pragma unroll
            for (int r = 0; r < 4; ++r) {
                const int d = dc * 16 + 4 * g + r;
                Out[(size_t)(q0 + qi) * D_ + d] =
                    (o[dc][r] + Obuf[qidx * 260 + d]) * inv;
            }
    }
}

extern "C" void kernel_launch(void* const* d_in, const int* in_sizes, int n_in,
                              void* d_out, int out_size, void* d_ws, size_t ws_size,
                              hipStream_t stream) {
    (void)out_size; (void)ws_size;
    const void *Xp = nullptr, *Wp = nullptr, *bp = nullptr;
    for (int i = 0; i < n_in; ++i) {
        if      (in_sizes[i] == B_ * S_ * D_) Xp = d_in[i];
        else if (in_sizes[i] == 3 * D_ * D_)  Wp = d_in[i];
        else if (in_sizes[i] == 3 * D_)       bp = d_in[i];
    }
    if (!Xp) Xp = d_in[0];
    if (!Wp) Wp = d_in[1];
    if (!bp) bp = d_in[2];

    float* Out = (float*)d_out;                                 // [B*S][256] f32

    unsigned short* Qb = (unsigned short*)d_ws;                 // 8 MiB
    unsigned short* Kb = Qb + (size_t)B_ * S_ * D_;             // 8 MiB
    unsigned short* Vt = Kb + (size_t)B_ * S_ * D_;             // 8 MiB
    // ws needed: 24 MiB

    dim3 pgrid(256, 12);
    qkv_proj<<<pgrid, 256, 0, stream>>>((const float*)Xp, (const float*)Wp,
                                        (const float*)bp, Qb, Kb, Vt);
    attn_fwd<<<256, 512, 0, stream>>>(Qb, Kb, Vt, Out);
}